// Round 2
// baseline (1842.909 us; speedup 1.0000x reference)
//
#include <hip/hip_runtime.h>
#include <hip/hip_bf16.h>

#define HID 128
#define EPB 16   // edges per block (edge encoder / fused msg)
#define NPB 16   // nodes per block (conv MLP)

__device__ __forceinline__ float eld(const float* p) { return *p; }
__device__ __forceinline__ float eld(const __hip_bfloat16* p) { return __bfloat162float(*p); }
__device__ __forceinline__ void est(float* p, float v) { *p = v; }
__device__ __forceinline__ void est(__hip_bfloat16* p, float v) { *p = __float2bfloat16(v); }

// ---------------- zero fill ----------------
__global__ void k_zero(float* __restrict__ p, size_t n) {
  size_t i = (size_t)blockIdx.x * blockDim.x + threadIdx.x;
  if (i < n) p[i] = 0.f;
}

// ---------------- node encoder: h = x @ node_w + node_b ----------------
__global__ void k_node_enc(const float* __restrict__ x, const float* __restrict__ w,
                           const float* __restrict__ b, float* __restrict__ h, int nN) {
  int idx = blockIdx.x * blockDim.x + threadIdx.x;
  if (idx >= nN * HID) return;
  int i = idx >> 7, j = idx & 127;
  float acc = b[j];
  const float* xr = x + (size_t)i * 7;
#pragma unroll
  for (int k = 0; k < 7; ++k) acc += xr[k] * w[k * HID + j];
  h[idx] = acc;
}

// ---------------- edge encoder: e = relu(ea @ w1 + b1) @ w2 + b2 ----------------
template <typename ET>
__global__ void __launch_bounds__(128) k_edge_enc(
    const float* __restrict__ ea, const float* __restrict__ w1, const float* __restrict__ b1,
    const float* __restrict__ w2, const float* __restrict__ b2, ET* __restrict__ e, int nE) {
  __shared__ __attribute__((aligned(16))) float ts[EPB][HID];
  int tid = threadIdx.x;
  int e0 = blockIdx.x * EPB;
  // stage 1: K=3 layer; thread = column tid, loop over the block's 16 edges
  float wa = w1[tid], wb = w1[HID + tid], wc = w1[2 * HID + tid];
  float bj = b1[tid];
#pragma unroll
  for (int i = 0; i < EPB; ++i) {
    int eid = e0 + i;
    float acc = bj;
    if (eid < nE) {
      const float* a = ea + (size_t)eid * 3;
      acc += a[0] * wa + a[1] * wb + a[2] * wc;
    }
    ts[i][tid] = fmaxf(acc, 0.f);
  }
  __syncthreads();
  // stage 2: K=128 GEMM. wave w -> edges [8w,8w+8), thread -> cols (lane, lane+64)
  int wave = tid >> 6, lane = tid & 63;
  int i0 = wave * (EPB / 2);
  float acc[EPB / 2][2];
  float c0 = b2[lane], c1 = b2[lane + 64];
#pragma unroll
  for (int i = 0; i < EPB / 2; ++i) { acc[i][0] = c0; acc[i][1] = c1; }
  for (int k = 0; k < HID; k += 4) {
    float w00 = w2[(k + 0) * HID + lane], w01 = w2[(k + 0) * HID + lane + 64];
    float w10 = w2[(k + 1) * HID + lane], w11 = w2[(k + 1) * HID + lane + 64];
    float w20 = w2[(k + 2) * HID + lane], w21 = w2[(k + 2) * HID + lane + 64];
    float w30 = w2[(k + 3) * HID + lane], w31 = w2[(k + 3) * HID + lane + 64];
#pragma unroll
    for (int i = 0; i < EPB / 2; ++i) {
      float4 t4 = *(const float4*)&ts[i0 + i][k];   // LDS broadcast, conflict-free
      acc[i][0] += t4.x * w00 + t4.y * w10 + t4.z * w20 + t4.w * w30;
      acc[i][1] += t4.x * w01 + t4.y * w11 + t4.z * w21 + t4.w * w31;
    }
  }
#pragma unroll
  for (int i = 0; i < EPB / 2; ++i) {
    int eid = e0 + i0 + i;
    if (eid < nE) {
      est(&e[(size_t)eid * HID + lane], acc[i][0]);
      est(&e[(size_t)eid * HID + lane + 64], acc[i][1]);
    }
  }
}

// ---------------- message + scatter: agg[dst] += relu(h[src] + e) ----------------
template <typename ET>
__global__ void k_msg(const float* __restrict__ h, const ET* __restrict__ e,
                      const int* __restrict__ src, const int* __restrict__ dst,
                      float* __restrict__ agg, int nE) {
  int idx = blockIdx.x * blockDim.x + threadIdx.x;
  int eid = idx >> 7;
  if (eid >= nE) return;
  int j = idx & 127;
  int s = src[eid], d = dst[eid];           // wave-uniform -> scalar loads
  float m = fmaxf(h[s * HID + j] + eld(&e[(size_t)eid * HID + j]), 0.f);
  atomicAdd(&agg[d * HID + j], m);
}

// ---------------- fused: recompute e and scatter (low-workspace path) ----------------
__global__ void __launch_bounds__(128) k_msg_fused(
    const float* __restrict__ ea, const float* __restrict__ w1, const float* __restrict__ b1,
    const float* __restrict__ w2, const float* __restrict__ b2,
    const float* __restrict__ h, const int* __restrict__ src, const int* __restrict__ dst,
    float* __restrict__ agg, int nE) {
  __shared__ __attribute__((aligned(16))) float ts[EPB][HID];
  int tid = threadIdx.x;
  int e0 = blockIdx.x * EPB;
  float wa = w1[tid], wb = w1[HID + tid], wc = w1[2 * HID + tid];
  float bj = b1[tid];
#pragma unroll
  for (int i = 0; i < EPB; ++i) {
    int eid = e0 + i;
    float acc = bj;
    if (eid < nE) {
      const float* a = ea + (size_t)eid * 3;
      acc += a[0] * wa + a[1] * wb + a[2] * wc;
    }
    ts[i][tid] = fmaxf(acc, 0.f);
  }
  __syncthreads();
  int wave = tid >> 6, lane = tid & 63;
  int i0 = wave * (EPB / 2);
  float acc[EPB / 2][2];
  float c0 = b2[lane], c1 = b2[lane + 64];
#pragma unroll
  for (int i = 0; i < EPB / 2; ++i) { acc[i][0] = c0; acc[i][1] = c1; }
  for (int k = 0; k < HID; k += 4) {
    float w00 = w2[(k + 0) * HID + lane], w01 = w2[(k + 0) * HID + lane + 64];
    float w10 = w2[(k + 1) * HID + lane], w11 = w2[(k + 1) * HID + lane + 64];
    float w20 = w2[(k + 2) * HID + lane], w21 = w2[(k + 2) * HID + lane + 64];
    float w30 = w2[(k + 3) * HID + lane], w31 = w2[(k + 3) * HID + lane + 64];
#pragma unroll
    for (int i = 0; i < EPB / 2; ++i) {
      float4 t4 = *(const float4*)&ts[i0 + i][k];
      acc[i][0] += t4.x * w00 + t4.y * w10 + t4.z * w20 + t4.w * w30;
      acc[i][1] += t4.x * w01 + t4.y * w11 + t4.z * w21 + t4.w * w31;
    }
  }
#pragma unroll
  for (int i = 0; i < EPB / 2; ++i) {
    int eid = e0 + i0 + i;
    if (eid < nE) {
      int s = src[eid], d = dst[eid];
      float m0 = fmaxf(h[(size_t)s * HID + lane] + acc[i][0], 0.f);
      float m1 = fmaxf(h[(size_t)s * HID + lane + 64] + acc[i][1], 0.f);
      atomicAdd(&agg[(size_t)d * HID + lane], m0);
      atomicAdd(&agg[(size_t)d * HID + lane + 64], m1);
    }
  }
}

// ---------------- conv MLP: h = relu(relu((h+agg)@w1+b1)@w2+b2), in-place ----------------
__global__ void __launch_bounds__(128) k_conv(
    const float* h, const float* agg,
    const float* __restrict__ w1, const float* __restrict__ b1,
    const float* __restrict__ w2, const float* __restrict__ b2,
    float* hout, int nN) {
  __shared__ __attribute__((aligned(16))) float zs[NPB][HID];
  __shared__ __attribute__((aligned(16))) float ts[NPB][HID];
  int tid = threadIdx.x;
  int n0 = blockIdx.x * NPB;
#pragma unroll
  for (int i = 0; i < NPB; ++i) {
    int n = n0 + i;
    float v = 0.f;
    if (n < nN) v = h[(size_t)n * HID + tid] + agg[(size_t)n * HID + tid];
    zs[i][tid] = v;
  }
  __syncthreads();
  int wave = tid >> 6, lane = tid & 63;
  int i0 = wave * (NPB / 2);
  float acc[NPB / 2][2];
  float b10 = b1[lane], b11 = b1[lane + 64];
#pragma unroll
  for (int i = 0; i < NPB / 2; ++i) { acc[i][0] = b10; acc[i][1] = b11; }
  for (int k = 0; k < HID; k += 4) {
    float w00 = w1[(k + 0) * HID + lane], w01 = w1[(k + 0) * HID + lane + 64];
    float w10 = w1[(k + 1) * HID + lane], w11 = w1[(k + 1) * HID + lane + 64];
    float w20 = w1[(k + 2) * HID + lane], w21 = w1[(k + 2) * HID + lane + 64];
    float w30 = w1[(k + 3) * HID + lane], w31 = w1[(k + 3) * HID + lane + 64];
#pragma unroll
    for (int i = 0; i < NPB / 2; ++i) {
      float4 z4 = *(const float4*)&zs[i0 + i][k];
      acc[i][0] += z4.x * w00 + z4.y * w10 + z4.z * w20 + z4.w * w30;
      acc[i][1] += z4.x * w01 + z4.y * w11 + z4.z * w21 + z4.w * w31;
    }
  }
#pragma unroll
  for (int i = 0; i < NPB / 2; ++i) {
    ts[i0 + i][lane] = fmaxf(acc[i][0], 0.f);
    ts[i0 + i][lane + 64] = fmaxf(acc[i][1], 0.f);
  }
  __syncthreads();
  float b20 = b2[lane], b21 = b2[lane + 64];
#pragma unroll
  for (int i = 0; i < NPB / 2; ++i) { acc[i][0] = b20; acc[i][1] = b21; }
  for (int k = 0; k < HID; k += 4) {
    float w00 = w2[(k + 0) * HID + lane], w01 = w2[(k + 0) * HID + lane + 64];
    float w10 = w2[(k + 1) * HID + lane], w11 = w2[(k + 1) * HID + lane + 64];
    float w20 = w2[(k + 2) * HID + lane], w21 = w2[(k + 2) * HID + lane + 64];
    float w30 = w2[(k + 3) * HID + lane], w31 = w2[(k + 3) * HID + lane + 64];
#pragma unroll
    for (int i = 0; i < NPB / 2; ++i) {
      float4 t4 = *(const float4*)&ts[i0 + i][k];
      acc[i][0] += t4.x * w00 + t4.y * w10 + t4.z * w20 + t4.w * w30;
      acc[i][1] += t4.x * w01 + t4.y * w11 + t4.z * w21 + t4.w * w31;
    }
  }
#pragma unroll
  for (int i = 0; i < NPB / 2; ++i) {
    int n = n0 + i0 + i;
    if (n < nN) {
      hout[(size_t)n * HID + lane] = fmaxf(acc[i][0], 0.f);
      hout[(size_t)n * HID + lane + 64] = fmaxf(acc[i][1], 0.f);
    }
  }
}

// ---------------- global mean pool (sum part) ----------------
__global__ void k_pool(const float* __restrict__ h, const int* __restrict__ batch,
                       float* __restrict__ g, int* __restrict__ counts, int nN) {
  int idx = blockIdx.x * blockDim.x + threadIdx.x;
  int i = idx >> 7;
  if (i >= nN) return;
  int j = idx & 127;
  int b = batch[i];
  atomicAdd(&g[b * HID + j], h[idx]);
  if (j == 0) atomicAdd(&counts[b], 1);
}

// ---------------- heads: mean + 2x (128->64 relu ->1) ----------------
__global__ void __launch_bounds__(128) k_head(
    const float* __restrict__ g, const int* __restrict__ counts,
    const float* __restrict__ clw1, const float* __restrict__ clb1,
    const float* __restrict__ clw2, const float* __restrict__ clb2,
    const float* __restrict__ rw1, const float* __restrict__ rb1,
    const float* __restrict__ rw2, const float* __restrict__ rb2,
    float* __restrict__ out, int nG) {
  __shared__ float gs[HID];
  int b = blockIdx.x;
  int tid = threadIdx.x;
  float cnt = fmaxf((float)counts[b], 1.f);
  gs[tid] = g[b * HID + tid] / cnt;
  __syncthreads();
  int wave = tid >> 6, lane = tid & 63;
  const float* w1 = wave ? rw1 : clw1;
  const float* b1 = wave ? rb1 : clb1;
  const float* w2 = wave ? rw2 : clw2;
  const float* b2 = wave ? rb2 : clb2;
  float acc = b1[lane];
  for (int k = 0; k < HID; ++k) acc += gs[k] * w1[k * 64 + lane];
  acc = fmaxf(acc, 0.f) * w2[lane];
#pragma unroll
  for (int off = 32; off; off >>= 1) acc += __shfl_down(acc, off);
  if (lane == 0) out[wave * nG + b] = acc + b2[0];
}

extern "C" void kernel_launch(void* const* d_in, const int* in_sizes, int n_in,
                              void* d_out, int out_size, void* d_ws, size_t ws_size,
                              hipStream_t stream) {
  const float* x      = (const float*)d_in[0];
  const float* ea     = (const float*)d_in[1];
  const int*   eidx   = (const int*)d_in[2];
  const int*   batch  = (const int*)d_in[3];
  const float* node_w = (const float*)d_in[4];
  const float* node_b = (const float*)d_in[5];
  const float* ew1    = (const float*)d_in[6];
  const float* eb1    = (const float*)d_in[7];
  const float* ew2    = (const float*)d_in[8];
  const float* eb2    = (const float*)d_in[9];
  const float* cw1    = (const float*)d_in[10];
  const float* cb1    = (const float*)d_in[11];
  const float* cw2    = (const float*)d_in[12];
  const float* cb2    = (const float*)d_in[13];
  const float* clw1   = (const float*)d_in[14];
  const float* clb1   = (const float*)d_in[15];
  const float* clw2   = (const float*)d_in[16];
  const float* clb2   = (const float*)d_in[17];
  const float* rw1    = (const float*)d_in[18];
  const float* rb1    = (const float*)d_in[19];
  const float* rw2    = (const float*)d_in[20];
  const float* rb2    = (const float*)d_in[21];
  float* out = (float*)d_out;

  int nN = in_sizes[3];        // 100000
  int nE = in_sizes[2] / 2;    // 640000
  int nG = out_size / 2;       // 2048
  const int* src = eidx;
  const int* dst = eidx + nE;

  // ---- workspace layout, tiered by ws_size (deterministic: same every call) ----
  // fixed part: h, agg, g, cnts  (~103.5 MB)
  size_t hN = (size_t)nN * HID;                  // floats
  size_t gN = (size_t)nG * HID;
  float* h    = (float*)d_ws;
  float* agg  = h + hN;
  float* g    = agg + hN;
  int*   cnts = (int*)(g + gN);
  char*  etail = (char*)(cnts + nG);             // 16B-aligned for our sizes
  size_t tail = (size_t)((char*)etail - (char*)d_ws);
  size_t eElems = (size_t)nE * HID;
  size_t need_f32 = tail + eElems * sizeof(float);
  size_t need_b16 = tail + eElems * sizeof(__hip_bfloat16);
  int mode = (ws_size >= need_f32) ? 0 : (ws_size >= need_b16 ? 1 : 2);

  float*          e32 = (float*)etail;
  __hip_bfloat16* e16 = (__hip_bfloat16*)etail;

  k_node_enc<<<(nN * HID + 255) / 256, 256, 0, stream>>>(x, node_w, node_b, h, nN);
  if (mode == 0)
    k_edge_enc<float><<<(nE + EPB - 1) / EPB, 128, 0, stream>>>(ea, ew1, eb1, ew2, eb2, e32, nE);
  else if (mode == 1)
    k_edge_enc<__hip_bfloat16><<<(nE + EPB - 1) / EPB, 128, 0, stream>>>(ea, ew1, eb1, ew2, eb2, e16, nE);

  int zeroBlocks = (int)((hN + 255) / 256);
  int msgBlocks = (int)((eElems + 255) / 256);
  for (int l = 0; l < 3; ++l) {
    k_zero<<<zeroBlocks, 256, 0, stream>>>(agg, hN);
    if (mode == 0)
      k_msg<float><<<msgBlocks, 256, 0, stream>>>(h, e32, src, dst, agg, nE);
    else if (mode == 1)
      k_msg<__hip_bfloat16><<<msgBlocks, 256, 0, stream>>>(h, e16, src, dst, agg, nE);
    else
      k_msg_fused<<<(nE + EPB - 1) / EPB, 128, 0, stream>>>(ea, ew1, eb1, ew2, eb2,
                                                            h, src, dst, agg, nE);
    k_conv<<<(nN + NPB - 1) / NPB, 128, 0, stream>>>(
        h, agg, cw1 + (size_t)l * HID * HID, cb1 + (size_t)l * HID,
        cw2 + (size_t)l * HID * HID, cb2 + (size_t)l * HID, h, nN);
  }

  // zero g (fp32) and cnts (int: zero bit-pattern identical)
  k_zero<<<(int)((gN + nG + 255) / 256), 256, 0, stream>>>(g, gN + nG);
  int poolBlocks = (int)((hN + 255) / 256);
  k_pool<<<poolBlocks, 256, 0, stream>>>(h, batch, g, cnts, nN);
  k_head<<<nG, 128, 0, stream>>>(g, cnts, clw1, clb1, clw2, clb2,
                                 rw1, rb1, rw2, rb2, out, nG);
}

// Round 3
// 1309.675 us; speedup vs baseline: 1.4072x; 1.4072x over previous
//
#include <hip/hip_runtime.h>

#define HID 128
#define LDP 136   // padded LDS row stride in bf16 elems (+8 spreads banks)

typedef short s16x8 __attribute__((ext_vector_type(8)));
typedef float f32x4 __attribute__((ext_vector_type(4)));

// bf16 (as ushort bits) -> f32: exact, just a shift
__device__ __forceinline__ float bf2f(unsigned int u) {
  union { unsigned int i; float f; } v; v.i = u << 16; return v.f;
}
// f32 -> bf16 bits, round-nearest-even
__device__ __forceinline__ unsigned short f2bf(float f) {
  union { float f; unsigned int i; } v; v.f = f;
  unsigned int r = v.i + 0x7fffu + ((v.i >> 16) & 1u);
  return (unsigned short)(r >> 16);
}

// ---------------- zero fill ----------------
__global__ void k_zero(float* __restrict__ p, size_t n) {
  size_t i = (size_t)blockIdx.x * blockDim.x + threadIdx.x;
  if (i < n) p[i] = 0.f;
}

// ---------------- transpose weights to bf16: wT[m][n*128+k] = w_m[k*128+n] ----------------
__global__ void k_prep_w(const float* __restrict__ ew2, const float* __restrict__ cw1,
                         const float* __restrict__ cw2, unsigned short* __restrict__ wT) {
  int idx = blockIdx.x * blockDim.x + threadIdx.x;   // 7*16384
  if (idx >= 7 * 16384) return;
  int m = idx >> 14, i = idx & 16383;
  int n = i >> 7, k = i & 127;
  const float* s = (m == 0) ? ew2 : (m <= 3 ? cw1 + (size_t)(m - 1) * 16384
                                            : cw2 + (size_t)(m - 4) * 16384);
  wT[idx] = f2bf(s[k * 128 + n]);
}

// ---------------- node encoder: h16 = bf16(x @ node_w + node_b) ----------------
__global__ void k_node_enc(const float* __restrict__ x, const float* __restrict__ w,
                           const float* __restrict__ b, unsigned short* __restrict__ h16, int nN) {
  int idx = blockIdx.x * blockDim.x + threadIdx.x;
  if (idx >= nN * HID) return;
  int i = idx >> 7, j = idx & 127;
  float acc = b[j];
  const float* xr = x + (size_t)i * 7;
#pragma unroll
  for (int k = 0; k < 7; ++k) acc += xr[k] * w[k * HID + j];
  h16[idx] = f2bf(acc);
}

// ---------------- fused edge-encoder GEMM + message + scatter ----------------
// block = 256 thr, 128 edges. e = relu(ea@w1+b1)@W2 + b2 via MFMA;
// epilogue: agg[dst] += relu(h16[src] + e)
__global__ void __launch_bounds__(256) k_msg_mfma(
    const float* __restrict__ ea, const float* __restrict__ ew1, const float* __restrict__ eb1,
    const unsigned short* __restrict__ w2t, const float* __restrict__ eb2,
    const unsigned short* __restrict__ h16,
    const int* __restrict__ src, const int* __restrict__ dst,
    float* __restrict__ agg, int nE) {
  __shared__ __attribute__((aligned(16))) unsigned short ts1[128 * LDP];
  __shared__ float eaL[128 * 3];
  int tid = threadIdx.x;
  int e0 = blockIdx.x * 128;                      // nE % 128 == 0
  for (int i = tid; i < 384; i += 256) eaL[i] = ea[(size_t)e0 * 3 + i];
  __syncthreads();
  // stage 1: T = relu(ea@w1+b1), bf16 into LDS
  {
    int j = tid & 127, r0 = (tid >> 7) * 64;
    float wa = ew1[j], wb = ew1[HID + j], wc = ew1[2 * HID + j], bj = eb1[j];
    for (int r = r0; r < r0 + 64; ++r) {
      float acc = bj + eaL[r * 3] * wa + eaL[r * 3 + 1] * wb + eaL[r * 3 + 2] * wc;
      ts1[r * LDP + j] = f2bf(fmaxf(acc, 0.f));
    }
  }
  __syncthreads();
  int wave = tid >> 6, lane = tid & 63;
  int l15 = lane & 15, quad = lane >> 4;
  int rbase = (wave >> 1) * 64, nbase = (wave & 1) * 64;
  f32x4 acc[4][4];
#pragma unroll
  for (int i = 0; i < 4; ++i)
#pragma unroll
    for (int j = 0; j < 4; ++j) acc[i][j] = (f32x4){0.f, 0.f, 0.f, 0.f};
  for (int kc = 0; kc < 4; ++kc) {
    int k0 = kc * 32 + quad * 8;
    s16x8 af[4], bf[4];
#pragma unroll
    for (int t = 0; t < 4; ++t)
      af[t] = *(const s16x8*)&ts1[(rbase + t * 16 + l15) * LDP + k0];
#pragma unroll
    for (int t = 0; t < 4; ++t)
      bf[t] = *(const s16x8*)&w2t[(size_t)(nbase + t * 16 + l15) * HID + k0];
#pragma unroll
    for (int i = 0; i < 4; ++i)
#pragma unroll
      for (int j = 0; j < 4; ++j)
        acc[i][j] = __builtin_amdgcn_mfma_f32_16x16x32_bf16(af[i], bf[j], acc[i][j], 0, 0, 0);
  }
  float ebv[4];
#pragma unroll
  for (int t = 0; t < 4; ++t) ebv[t] = eb2[nbase + t * 16 + l15];
#pragma unroll
  for (int tr = 0; tr < 4; ++tr) {
#pragma unroll
    for (int reg = 0; reg < 4; ++reg) {
      int row = rbase + tr * 16 + quad * 4 + reg;   // C/D: col=lane&15, row=quad*4+reg
      int s = src[e0 + row], d = dst[e0 + row];
      const unsigned short* hp = h16 + (size_t)s * HID;
      float* ap = agg + (size_t)d * HID;
#pragma unroll
      for (int tc = 0; tc < 4; ++tc) {
        int col = nbase + tc * 16 + l15;
        float m = fmaxf(bf2f(hp[col]) + acc[tr][tc][reg] + ebv[tc], 0.f);
        atomicAdd(ap + col, m);
      }
    }
  }
}

// ---------------- conv MLP: h16 = bf16(relu(relu((h+agg)@W1+b1)@W2+b2)) ----------------
__global__ void __launch_bounds__(256) k_conv_mfma(
    const unsigned short* __restrict__ h16in, const float* __restrict__ agg,
    const unsigned short* __restrict__ w1t, const float* __restrict__ b1,
    const unsigned short* __restrict__ w2t, const float* __restrict__ b2,
    unsigned short* __restrict__ h16out, int nN) {
  __shared__ __attribute__((aligned(16))) unsigned short zs[128 * LDP];
  int tid = threadIdx.x;
  int n0 = blockIdx.x * 128;
  // stage z = h + agg as bf16 into LDS
  for (int it = 0; it < 16; ++it) {
    int elem = (it * 256 + tid) * 4;
    int r = elem >> 7, c = elem & 127;
    int grow = n0 + r;
    uint2 zp = {0u, 0u};
    if (grow < nN) {
      uint2 hu = *(const uint2*)(h16in + (size_t)grow * HID + c);
      float4 a4 = *(const float4*)(agg + (size_t)grow * HID + c);
      unsigned short z0 = f2bf(bf2f(hu.x & 0xffffu) + a4.x);
      unsigned short z1 = f2bf(bf2f(hu.x >> 16) + a4.y);
      unsigned short z2 = f2bf(bf2f(hu.y & 0xffffu) + a4.z);
      unsigned short z3 = f2bf(bf2f(hu.y >> 16) + a4.w);
      zp.x = (unsigned int)z0 | ((unsigned int)z1 << 16);
      zp.y = (unsigned int)z2 | ((unsigned int)z3 << 16);
    }
    *(uint2*)&zs[r * LDP + c] = zp;
  }
  __syncthreads();
  int wave = tid >> 6, lane = tid & 63;
  int l15 = lane & 15, quad = lane >> 4;
  int rbase = (wave >> 1) * 64, nbase = (wave & 1) * 64;
  f32x4 acc[4][4];
#pragma unroll
  for (int i = 0; i < 4; ++i)
#pragma unroll
    for (int j = 0; j < 4; ++j) acc[i][j] = (f32x4){0.f, 0.f, 0.f, 0.f};
  // GEMM1: zs @ W1
  for (int kc = 0; kc < 4; ++kc) {
    int k0 = kc * 32 + quad * 8;
    s16x8 af[4], bf[4];
#pragma unroll
    for (int t = 0; t < 4; ++t)
      af[t] = *(const s16x8*)&zs[(rbase + t * 16 + l15) * LDP + k0];
#pragma unroll
    for (int t = 0; t < 4; ++t)
      bf[t] = *(const s16x8*)&w1t[(size_t)(nbase + t * 16 + l15) * HID + k0];
#pragma unroll
    for (int i = 0; i < 4; ++i)
#pragma unroll
      for (int j = 0; j < 4; ++j)
        acc[i][j] = __builtin_amdgcn_mfma_f32_16x16x32_bf16(af[i], bf[j], acc[i][j], 0, 0, 0);
  }
  __syncthreads();   // all zs reads done before overwrite
  // T = relu(acc + b1) back into zs (bf16)
  {
    float bv[4];
#pragma unroll
    for (int t = 0; t < 4; ++t) bv[t] = b1[nbase + t * 16 + l15];
#pragma unroll
    for (int tr = 0; tr < 4; ++tr)
#pragma unroll
      for (int tc = 0; tc < 4; ++tc)
#pragma unroll
        for (int reg = 0; reg < 4; ++reg) {
          int row = rbase + tr * 16 + quad * 4 + reg;
          int col = nbase + tc * 16 + l15;
          zs[row * LDP + col] = f2bf(fmaxf(acc[tr][tc][reg] + bv[tc], 0.f));
        }
  }
  __syncthreads();
  // GEMM2: T @ W2
#pragma unroll
  for (int i = 0; i < 4; ++i)
#pragma unroll
    for (int j = 0; j < 4; ++j) acc[i][j] = (f32x4){0.f, 0.f, 0.f, 0.f};
  for (int kc = 0; kc < 4; ++kc) {
    int k0 = kc * 32 + quad * 8;
    s16x8 af[4], bf[4];
#pragma unroll
    for (int t = 0; t < 4; ++t)
      af[t] = *(const s16x8*)&zs[(rbase + t * 16 + l15) * LDP + k0];
#pragma unroll
    for (int t = 0; t < 4; ++t)
      bf[t] = *(const s16x8*)&w2t[(size_t)(nbase + t * 16 + l15) * HID + k0];
#pragma unroll
    for (int i = 0; i < 4; ++i)
#pragma unroll
      for (int j = 0; j < 4; ++j)
        acc[i][j] = __builtin_amdgcn_mfma_f32_16x16x32_bf16(af[i], bf[j], acc[i][j], 0, 0, 0);
  }
  // epilogue: h16out = bf16(relu(acc + b2))
  {
    float bv[4];
#pragma unroll
    for (int t = 0; t < 4; ++t) bv[t] = b2[nbase + t * 16 + l15];
#pragma unroll
    for (int tr = 0; tr < 4; ++tr)
#pragma unroll
      for (int reg = 0; reg < 4; ++reg) {
        int grow = n0 + rbase + tr * 16 + quad * 4 + reg;
        if (grow < nN) {
#pragma unroll
          for (int tc = 0; tc < 4; ++tc) {
            int col = nbase + tc * 16 + l15;
            h16out[(size_t)grow * HID + col] = f2bf(fmaxf(acc[tr][tc][reg] + bv[tc], 0.f));
          }
        }
      }
  }
}

// ---------------- global mean pool (sum part) ----------------
__global__ void k_pool(const unsigned short* __restrict__ h16, const int* __restrict__ batch,
                       float* __restrict__ g, int* __restrict__ counts, int nN) {
  int idx = blockIdx.x * blockDim.x + threadIdx.x;
  int i = idx >> 7;
  if (i >= nN) return;
  int j = idx & 127;
  int b = batch[i];
  atomicAdd(&g[b * HID + j], bf2f(h16[idx]));
  if (j == 0) atomicAdd(&counts[b], 1);
}

// ---------------- heads ----------------
__global__ void __launch_bounds__(128) k_head(
    const float* __restrict__ g, const int* __restrict__ counts,
    const float* __restrict__ clw1, const float* __restrict__ clb1,
    const float* __restrict__ clw2, const float* __restrict__ clb2,
    const float* __restrict__ rw1, const float* __restrict__ rb1,
    const float* __restrict__ rw2, const float* __restrict__ rb2,
    float* __restrict__ out, int nG) {
  __shared__ float gs[HID];
  int b = blockIdx.x;
  int tid = threadIdx.x;
  float cnt = fmaxf((float)counts[b], 1.f);
  gs[tid] = g[b * HID + tid] / cnt;
  __syncthreads();
  int wave = tid >> 6, lane = tid & 63;
  const float* w1 = wave ? rw1 : clw1;
  const float* b1 = wave ? rb1 : clb1;
  const float* w2 = wave ? rw2 : clw2;
  const float* b2 = wave ? rb2 : clb2;
  float acc = b1[lane];
  for (int k = 0; k < HID; ++k) acc += gs[k] * w1[k * 64 + lane];
  acc = fmaxf(acc, 0.f) * w2[lane];
#pragma unroll
  for (int off = 32; off; off >>= 1) acc += __shfl_down(acc, off);
  if (lane == 0) out[wave * nG + b] = acc + b2[0];
}

extern "C" void kernel_launch(void* const* d_in, const int* in_sizes, int n_in,
                              void* d_out, int out_size, void* d_ws, size_t ws_size,
                              hipStream_t stream) {
  const float* x      = (const float*)d_in[0];
  const float* ea     = (const float*)d_in[1];
  const int*   eidx   = (const int*)d_in[2];
  const int*   batch  = (const int*)d_in[3];
  const float* node_w = (const float*)d_in[4];
  const float* node_b = (const float*)d_in[5];
  const float* ew1    = (const float*)d_in[6];
  const float* eb1    = (const float*)d_in[7];
  const float* ew2    = (const float*)d_in[8];
  const float* eb2    = (const float*)d_in[9];
  const float* cw1    = (const float*)d_in[10];
  const float* cb1    = (const float*)d_in[11];
  const float* cw2    = (const float*)d_in[12];
  const float* cb2    = (const float*)d_in[13];
  const float* clw1   = (const float*)d_in[14];
  const float* clb1   = (const float*)d_in[15];
  const float* clw2   = (const float*)d_in[16];
  const float* clb2   = (const float*)d_in[17];
  const float* rw1    = (const float*)d_in[18];
  const float* rb1    = (const float*)d_in[19];
  const float* rw2    = (const float*)d_in[20];
  const float* rb2    = (const float*)d_in[21];
  float* out = (float*)d_out;

  int nN = in_sizes[3];        // 100000
  int nE = in_sizes[2] / 2;    // 640000 (divisible by 128)
  int nG = out_size / 2;       // 2048
  const int* src = eidx;
  const int* dst = eidx + nE;

  // workspace (~78 MB): agg | g | cnts | wT(7x128x128 bf16) | h16
  size_t hN = (size_t)nN * HID;
  size_t gN = (size_t)nG * HID;
  float* agg = (float*)d_ws;
  float* g   = agg + hN;
  int*   cnts = (int*)(g + gN);
  unsigned short* wT  = (unsigned short*)(cnts + nG);
  unsigned short* h16 = wT + 7 * 16384;

  k_prep_w<<<(7 * 16384 + 255) / 256, 256, 0, stream>>>(ew2, cw1, cw2, wT);
  k_node_enc<<<(nN * HID + 255) / 256, 256, 0, stream>>>(x, node_w, node_b, h16, nN);

  int zeroBlocks = (int)((hN + 255) / 256);
  for (int l = 0; l < 3; ++l) {
    k_zero<<<zeroBlocks, 256, 0, stream>>>(agg, hN);
    k_msg_mfma<<<nE / 128, 256, 0, stream>>>(ea, ew1, eb1, wT, eb2, h16, src, dst, agg, nE);
    k_conv_mfma<<<(nN + 127) / 128, 256, 0, stream>>>(
        h16, agg, wT + (size_t)(1 + l) * 16384, cb1 + (size_t)l * HID,
        wT + (size_t)(4 + l) * 16384, cb2 + (size_t)l * HID, h16, nN);
  }

  k_zero<<<(int)((gN + nG + 255) / 256), 256, 0, stream>>>(g, gN + nG);
  k_pool<<<(int)((hN + 255) / 256), 256, 0, stream>>>(h16, batch, g, cnts, nN);
  k_head<<<nG, 128, 0, stream>>>(g, cnts, clw1, clb1, clw2, clb2,
                                 rw1, rb1, rw2, rb2, out, nG);
}

// Round 4
// 1037.327 us; speedup vs baseline: 1.7766x; 1.2625x over previous
//
#include <hip/hip_runtime.h>

#define HID 128
#define LDP 136   // padded LDS row stride in bf16 elems

typedef short s16x8 __attribute__((ext_vector_type(8)));
typedef float f32x4 __attribute__((ext_vector_type(4)));

__device__ __forceinline__ float bf2f(unsigned int u) {
  union { unsigned int i; float f; } v; v.i = u << 16; return v.f;
}
__device__ __forceinline__ unsigned short f2bf(float f) {
  union { float f; unsigned int i; } v; v.f = f;
  unsigned int r = v.i + 0x7fffu + ((v.i >> 16) & 1u);
  return (unsigned short)(r >> 16);
}

// ---------------- zero fill ----------------
__global__ void k_zero(float* __restrict__ p, size_t n) {
  size_t i = (size_t)blockIdx.x * blockDim.x + threadIdx.x;
  if (i < n) p[i] = 0.f;
}

// ---------------- counting sort: histogram ----------------
__global__ void k_hist(const int* __restrict__ dst, int* __restrict__ deg, int nE) {
  int e = blockIdx.x * blockDim.x + threadIdx.x;
  if (e < nE) atomicAdd(&deg[dst[e]], 1);
}

// per-block sums of deg (256/block)
__global__ void k_scanA(const int* __restrict__ deg, int* __restrict__ bsum) {
  __shared__ int ss[256];
  int t = threadIdx.x;
  ss[t] = deg[blockIdx.x * 256 + t];
  __syncthreads();
  for (int off = 128; off; off >>= 1) {
    if (t < off) ss[t] += ss[t + off];
    __syncthreads();
  }
  if (t == 0) bsum[blockIdx.x] = ss[0];
}

// exclusive scan of block sums (single block, NB<=512)
__global__ void k_scanB(const int* __restrict__ bsum, int* __restrict__ bsumx, int NB) {
  __shared__ int sd[512];
  int t = threadIdx.x;
  int v = (t < NB) ? bsum[t] : 0;
  sd[t] = v;
  __syncthreads();
  for (int off = 1; off < 512; off <<= 1) {
    int a = (t >= off) ? sd[t - off] : 0;
    __syncthreads();
    sd[t] += a;
    __syncthreads();
  }
  if (t < NB) bsumx[t] = sd[t] - v;
}

// final: cursor[i] = exclusive_scan(deg)[i]
__global__ void k_scanC(const int* __restrict__ deg, const int* __restrict__ bsumx,
                        int* __restrict__ cursor) {
  __shared__ int ss[256];
  int t = threadIdx.x, i = blockIdx.x * 256 + t;
  int v = deg[i];
  ss[t] = v;
  __syncthreads();
  for (int off = 1; off < 256; off <<= 1) {
    int a = (t >= off) ? ss[t - off] : 0;
    __syncthreads();
    ss[t] += a;
    __syncthreads();
  }
  cursor[i] = ss[t] - v + bsumx[blockIdx.x];
}

// scatter edges into dst-sorted order, pre-gathering ea/src/dst
__global__ void k_scatter(const int* __restrict__ src, const int* __restrict__ dst,
                          const float* __restrict__ ea, int* __restrict__ cursor,
                          int* __restrict__ src_s, int* __restrict__ dst_s,
                          float* __restrict__ ea_s, int nE) {
  int e = blockIdx.x * blockDim.x + threadIdx.x;
  if (e >= nE) return;
  int d = dst[e];
  int pos = atomicAdd(&cursor[d], 1);
  src_s[pos] = src[e];
  dst_s[pos] = d;
  ea_s[(size_t)pos * 3 + 0] = ea[(size_t)e * 3 + 0];
  ea_s[(size_t)pos * 3 + 1] = ea[(size_t)e * 3 + 1];
  ea_s[(size_t)pos * 3 + 2] = ea[(size_t)e * 3 + 2];
}

// ---------------- transpose weights to bf16: wT[m][n*128+k] = w_m[k*128+n] ----------------
__global__ void k_prep_w(const float* __restrict__ ew2, const float* __restrict__ cw1,
                         const float* __restrict__ cw2, unsigned short* __restrict__ wT) {
  int idx = blockIdx.x * blockDim.x + threadIdx.x;
  if (idx >= 7 * 16384) return;
  int m = idx >> 14, i = idx & 16383;
  int n = i >> 7, k = i & 127;
  const float* s = (m == 0) ? ew2 : (m <= 3 ? cw1 + (size_t)(m - 1) * 16384
                                            : cw2 + (size_t)(m - 4) * 16384);
  wT[idx] = f2bf(s[k * 128 + n]);
}

// ---------------- node encoder ----------------
__global__ void k_node_enc(const float* __restrict__ x, const float* __restrict__ w,
                           const float* __restrict__ b, unsigned short* __restrict__ h16, int nN) {
  int idx = blockIdx.x * blockDim.x + threadIdx.x;
  if (idx >= nN * HID) return;
  int i = idx >> 7, j = idx & 127;
  float acc = b[j];
  const float* xr = x + (size_t)i * 7;
#pragma unroll
  for (int k = 0; k < 7; ++k) acc += xr[k] * w[k * HID + j];
  h16[idx] = f2bf(acc);
}

// ---------------- fused edge GEMM + message + segment-reduced scatter ----------------
// edges pre-sorted by dst. block=256, 128 edges/tile.
__global__ void __launch_bounds__(256) k_msg2(
    const float* __restrict__ ea_s, const float* __restrict__ ew1, const float* __restrict__ eb1,
    const unsigned short* __restrict__ w2t, const float* __restrict__ eb2,
    const unsigned short* __restrict__ h16,
    const int* __restrict__ src_s, const int* __restrict__ dst_s,
    float* __restrict__ agg, int nE) {
  __shared__ __attribute__((aligned(16))) unsigned short ts1[128 * LDP];
  __shared__ float eaL[384];
  __shared__ int dstL[128];
  int tid = threadIdx.x;
  int e0 = blockIdx.x * 128;                      // nE % 128 == 0
  for (int i = tid; i < 384; i += 256) eaL[i] = ea_s[(size_t)e0 * 3 + i];
  if (tid < 128) dstL[tid] = dst_s[e0 + tid];
  __syncthreads();
  // stage 1: T = relu(ea@w1+b1) bf16 -> ts1
  {
    int j = tid & 127, r0 = (tid >> 7) * 64;
    float wa = ew1[j], wb = ew1[HID + j], wc = ew1[2 * HID + j], bj = eb1[j];
    for (int r = r0; r < r0 + 64; ++r) {
      float a = bj + eaL[r * 3] * wa + eaL[r * 3 + 1] * wb + eaL[r * 3 + 2] * wc;
      ts1[r * LDP + j] = f2bf(fmaxf(a, 0.f));
    }
  }
  __syncthreads();
  int wave = tid >> 6, lane = tid & 63;
  int l15 = lane & 15, quad = lane >> 4;
  int rbase = (wave >> 1) * 64, nbase = (wave & 1) * 64;
  f32x4 acc[4][4];
#pragma unroll
  for (int i = 0; i < 4; ++i)
#pragma unroll
    for (int j = 0; j < 4; ++j) acc[i][j] = (f32x4){0.f, 0.f, 0.f, 0.f};
  for (int kc = 0; kc < 4; ++kc) {
    int k0 = kc * 32 + quad * 8;
    s16x8 af[4], bf[4];
#pragma unroll
    for (int t = 0; t < 4; ++t)
      af[t] = *(const s16x8*)&ts1[(rbase + t * 16 + l15) * LDP + k0];
#pragma unroll
    for (int t = 0; t < 4; ++t)
      bf[t] = *(const s16x8*)&w2t[(size_t)(nbase + t * 16 + l15) * HID + k0];
#pragma unroll
    for (int i = 0; i < 4; ++i)
#pragma unroll
      for (int j = 0; j < 4; ++j)
        acc[i][j] = __builtin_amdgcn_mfma_f32_16x16x32_bf16(af[i], bf[j], acc[i][j], 0, 0, 0);
  }
  __syncthreads();   // all A-fragment reads done before m overwrites ts1
  // epilogue: m = relu(h[src] + e + b2) -> ts1 (bf16)
  {
    float ebv[4];
#pragma unroll
    for (int t = 0; t < 4; ++t) ebv[t] = eb2[nbase + t * 16 + l15];
#pragma unroll
    for (int tr = 0; tr < 4; ++tr) {
#pragma unroll
      for (int reg = 0; reg < 4; ++reg) {
        int row = rbase + tr * 16 + quad * 4 + reg;   // C/D: col=lane&15, row=quad*4+reg
        int s = src_s[e0 + row];
        const unsigned short* hp = h16 + (size_t)s * HID;
#pragma unroll
        for (int tc = 0; tc < 4; ++tc) {
          int col = nbase + tc * 16 + l15;
          float m = fmaxf(bf2f(hp[col]) + acc[tr][tc][reg] + ebv[tc], 0.f);
          ts1[row * LDP + col] = f2bf(m);
        }
      }
    }
  }
  __syncthreads();
  // segment-reduced scatter: each thread walks 64 rows of one column.
  // dst-sorted rows -> run-length sum, one atomic per (segment, col).
  {
    int half = tid >> 7, col = tid & 127;
    int rs = half * 64;
    int cur = -1;
    float s = 0.f;
    for (int r = rs; r < rs + 64; ++r) {
      int d = dstL[r];                              // LDS broadcast, wave-uniform
      float v = bf2f((unsigned int)ts1[r * LDP + col]);
      if (d != cur) {
        if (cur >= 0) atomicAdd(&agg[(size_t)cur * HID + col], s);
        cur = d; s = v;
      } else s += v;
    }
    if (cur >= 0) atomicAdd(&agg[(size_t)cur * HID + col], s);
  }
}

// ---------------- conv MLP ----------------
__global__ void __launch_bounds__(256) k_conv_mfma(
    const unsigned short* __restrict__ h16in, const float* __restrict__ agg,
    const unsigned short* __restrict__ w1t, const float* __restrict__ b1,
    const unsigned short* __restrict__ w2t, const float* __restrict__ b2,
    unsigned short* __restrict__ h16out, int nN) {
  __shared__ __attribute__((aligned(16))) unsigned short zs[128 * LDP];
  int tid = threadIdx.x;
  int n0 = blockIdx.x * 128;
  for (int it = 0; it < 16; ++it) {
    int elem = (it * 256 + tid) * 4;
    int r = elem >> 7, c = elem & 127;
    int grow = n0 + r;
    uint2 zp = {0u, 0u};
    if (grow < nN) {
      uint2 hu = *(const uint2*)(h16in + (size_t)grow * HID + c);
      float4 a4 = *(const float4*)(agg + (size_t)grow * HID + c);
      unsigned short z0 = f2bf(bf2f(hu.x & 0xffffu) + a4.x);
      unsigned short z1 = f2bf(bf2f(hu.x >> 16) + a4.y);
      unsigned short z2 = f2bf(bf2f(hu.y & 0xffffu) + a4.z);
      unsigned short z3 = f2bf(bf2f(hu.y >> 16) + a4.w);
      zp.x = (unsigned int)z0 | ((unsigned int)z1 << 16);
      zp.y = (unsigned int)z2 | ((unsigned int)z3 << 16);
    }
    *(uint2*)&zs[r * LDP + c] = zp;
  }
  __syncthreads();
  int wave = tid >> 6, lane = tid & 63;
  int l15 = lane & 15, quad = lane >> 4;
  int rbase = (wave >> 1) * 64, nbase = (wave & 1) * 64;
  f32x4 acc[4][4];
#pragma unroll
  for (int i = 0; i < 4; ++i)
#pragma unroll
    for (int j = 0; j < 4; ++j) acc[i][j] = (f32x4){0.f, 0.f, 0.f, 0.f};
  for (int kc = 0; kc < 4; ++kc) {
    int k0 = kc * 32 + quad * 8;
    s16x8 af[4], bf[4];
#pragma unroll
    for (int t = 0; t < 4; ++t)
      af[t] = *(const s16x8*)&zs[(rbase + t * 16 + l15) * LDP + k0];
#pragma unroll
    for (int t = 0; t < 4; ++t)
      bf[t] = *(const s16x8*)&w1t[(size_t)(nbase + t * 16 + l15) * HID + k0];
#pragma unroll
    for (int i = 0; i < 4; ++i)
#pragma unroll
      for (int j = 0; j < 4; ++j)
        acc[i][j] = __builtin_amdgcn_mfma_f32_16x16x32_bf16(af[i], bf[j], acc[i][j], 0, 0, 0);
  }
  __syncthreads();
  {
    float bv[4];
#pragma unroll
    for (int t = 0; t < 4; ++t) bv[t] = b1[nbase + t * 16 + l15];
#pragma unroll
    for (int tr = 0; tr < 4; ++tr)
#pragma unroll
      for (int tc = 0; tc < 4; ++tc)
#pragma unroll
        for (int reg = 0; reg < 4; ++reg) {
          int row = rbase + tr * 16 + quad * 4 + reg;
          int col = nbase + tc * 16 + l15;
          zs[row * LDP + col] = f2bf(fmaxf(acc[tr][tc][reg] + bv[tc], 0.f));
        }
  }
  __syncthreads();
#pragma unroll
  for (int i = 0; i < 4; ++i)
#pragma unroll
    for (int j = 0; j < 4; ++j) acc[i][j] = (f32x4){0.f, 0.f, 0.f, 0.f};
  for (int kc = 0; kc < 4; ++kc) {
    int k0 = kc * 32 + quad * 8;
    s16x8 af[4], bf[4];
#pragma unroll
    for (int t = 0; t < 4; ++t)
      af[t] = *(const s16x8*)&zs[(rbase + t * 16 + l15) * LDP + k0];
#pragma unroll
    for (int t = 0; t < 4; ++t)
      bf[t] = *(const s16x8*)&w2t[(size_t)(nbase + t * 16 + l15) * HID + k0];
#pragma unroll
    for (int i = 0; i < 4; ++i)
#pragma unroll
      for (int j = 0; j < 4; ++j)
        acc[i][j] = __builtin_amdgcn_mfma_f32_16x16x32_bf16(af[i], bf[j], acc[i][j], 0, 0, 0);
  }
  {
    float bv[4];
#pragma unroll
    for (int t = 0; t < 4; ++t) bv[t] = b2[nbase + t * 16 + l15];
#pragma unroll
    for (int tr = 0; tr < 4; ++tr)
#pragma unroll
      for (int reg = 0; reg < 4; ++reg) {
        int grow = n0 + rbase + tr * 16 + quad * 4 + reg;
        if (grow < nN) {
#pragma unroll
          for (int tc = 0; tc < 4; ++tc) {
            int col = nbase + tc * 16 + l15;
            h16out[(size_t)grow * HID + col] = f2bf(fmaxf(acc[tr][tc][reg] + bv[tc], 0.f));
          }
        }
      }
  }
}

// ---------------- counts (per-graph node count) ----------------
__global__ void k_counts(const int* __restrict__ batch, int* __restrict__ cnts, int nN) {
  int i = blockIdx.x * blockDim.x + threadIdx.x;
  if (i < nN) atomicAdd(&cnts[batch[i]], 1);
}

// ---------------- segment-reduced pool (batch is sorted) ----------------
__global__ void __launch_bounds__(256) k_pool2(
    const unsigned short* __restrict__ h16, const int* __restrict__ batch,
    float* __restrict__ g, int nN) {
  __shared__ int bL[128];
  int tid = threadIdx.x;
  int n0 = blockIdx.x * 128;
  if (tid < 128) {
    int n = n0 + tid;
    bL[tid] = (n < nN) ? batch[n] : -1;
  }
  __syncthreads();
  int half = tid >> 7, col = tid & 127;
  int rs = half * 64;
  int cur = -1;
  float s = 0.f;
  for (int r = rs; r < rs + 64; ++r) {
    int b = bL[r];
    float v = (b >= 0) ? bf2f((unsigned int)h16[(size_t)(n0 + r) * HID + col]) : 0.f;
    if (b != cur) {
      if (cur >= 0) atomicAdd(&g[(size_t)cur * HID + col], s);
      cur = b; s = v;
    } else s += v;
  }
  if (cur >= 0) atomicAdd(&g[(size_t)cur * HID + col], s);
}

// ---------------- heads ----------------
__global__ void __launch_bounds__(128) k_head(
    const float* __restrict__ g, const int* __restrict__ counts,
    const float* __restrict__ clw1, const float* __restrict__ clb1,
    const float* __restrict__ clw2, const float* __restrict__ clb2,
    const float* __restrict__ rw1, const float* __restrict__ rb1,
    const float* __restrict__ rw2, const float* __restrict__ rb2,
    float* __restrict__ out, int nG) {
  __shared__ float gs[HID];
  int b = blockIdx.x;
  int tid = threadIdx.x;
  float cnt = fmaxf((float)counts[b], 1.f);
  gs[tid] = g[b * HID + tid] / cnt;
  __syncthreads();
  int wave = tid >> 6, lane = tid & 63;
  const float* w1 = wave ? rw1 : clw1;
  const float* b1 = wave ? rb1 : clb1;
  const float* w2 = wave ? rw2 : clw2;
  const float* b2 = wave ? rb2 : clb2;
  float acc = b1[lane];
  for (int k = 0; k < HID; ++k) acc += gs[k] * w1[k * 64 + lane];
  acc = fmaxf(acc, 0.f) * w2[lane];
#pragma unroll
  for (int off = 32; off; off >>= 1) acc += __shfl_down(acc, off);
  if (lane == 0) out[wave * nG + b] = acc + b2[0];
}

extern "C" void kernel_launch(void* const* d_in, const int* in_sizes, int n_in,
                              void* d_out, int out_size, void* d_ws, size_t ws_size,
                              hipStream_t stream) {
  const float* x      = (const float*)d_in[0];
  const float* ea     = (const float*)d_in[1];
  const int*   eidx   = (const int*)d_in[2];
  const int*   batch  = (const int*)d_in[3];
  const float* node_w = (const float*)d_in[4];
  const float* node_b = (const float*)d_in[5];
  const float* ew1    = (const float*)d_in[6];
  const float* eb1    = (const float*)d_in[7];
  const float* ew2    = (const float*)d_in[8];
  const float* eb2    = (const float*)d_in[9];
  const float* cw1    = (const float*)d_in[10];
  const float* cb1    = (const float*)d_in[11];
  const float* cw2    = (const float*)d_in[12];
  const float* cb2    = (const float*)d_in[13];
  const float* clw1   = (const float*)d_in[14];
  const float* clb1   = (const float*)d_in[15];
  const float* clw2   = (const float*)d_in[16];
  const float* clb2   = (const float*)d_in[17];
  const float* rw1    = (const float*)d_in[18];
  const float* rb1    = (const float*)d_in[19];
  const float* rw2    = (const float*)d_in[20];
  const float* rb2    = (const float*)d_in[21];
  float* out = (float*)d_out;

  int nN = in_sizes[3];        // 100000
  int nE = in_sizes[2] / 2;    // 640000 (divisible by 128)
  int nG = out_size / 2;       // 2048
  const int* src = eidx;
  const int* dst = eidx + nE;

  int NB = (nN + 255) / 256;   // scan blocks (391)
  int bins = NB * 256;

  // ---- workspace (~92 MB) ----
  size_t hN = (size_t)nN * HID;
  size_t gN = (size_t)nG * HID;
  float* agg = (float*)d_ws;                        // hN f32
  float* g   = agg + hN;                            // gN f32
  int*   cnts = (int*)(g + gN);                     // nG
  unsigned short* wT  = (unsigned short*)(cnts + nG);  // 7*16384 bf16
  unsigned short* h16 = wT + 7 * 16384;             // hN bf16
  int* deg    = (int*)(h16 + hN);                   // bins
  int* cursor = deg + bins;                         // bins
  int* bsum   = cursor + bins;                      // NB
  int* bsumx  = bsum + NB;                          // NB
  int* src_s  = bsumx + NB;                         // nE
  int* dst_s  = src_s + nE;                         // nE
  float* ea_s = (float*)(dst_s + nE);               // 3*nE f32

  // ---- counting sort of edges by dst (per call; inputs restored each call) ----
  k_zero<<<(bins + 255) / 256, 256, 0, stream>>>((float*)deg, bins);
  k_hist<<<(nE + 255) / 256, 256, 0, stream>>>(dst, deg, nE);
  k_scanA<<<NB, 256, 0, stream>>>(deg, bsum);
  k_scanB<<<1, 512, 0, stream>>>(bsum, bsumx, NB);
  k_scanC<<<NB, 256, 0, stream>>>(deg, bsumx, cursor);
  k_scatter<<<(nE + 255) / 256, 256, 0, stream>>>(src, dst, ea, cursor,
                                                  src_s, dst_s, ea_s, nE);

  k_prep_w<<<(7 * 16384 + 255) / 256, 256, 0, stream>>>(ew2, cw1, cw2, wT);
  k_node_enc<<<(nN * HID + 255) / 256, 256, 0, stream>>>(x, node_w, node_b, h16, nN);

  int zeroBlocks = (int)((hN + 255) / 256);
  for (int l = 0; l < 3; ++l) {
    k_zero<<<zeroBlocks, 256, 0, stream>>>(agg, hN);
    k_msg2<<<nE / 128, 256, 0, stream>>>(ea_s, ew1, eb1, wT, eb2, h16,
                                         src_s, dst_s, agg, nE);
    k_conv_mfma<<<(nN + 127) / 128, 256, 0, stream>>>(
        h16, agg, wT + (size_t)(1 + l) * 16384, cb1 + (size_t)l * HID,
        wT + (size_t)(4 + l) * 16384, cb2 + (size_t)l * HID, h16, nN);
  }

  k_zero<<<(int)((gN + nG + 255) / 256), 256, 0, stream>>>(g, gN + nG);
  k_counts<<<(nN + 255) / 256, 256, 0, stream>>>(batch, cnts, nN);
  k_pool2<<<(nN + 127) / 128, 256, 0, stream>>>(h16, batch, g, nN);
  k_head<<<nG, 128, 0, stream>>>(g, cnts, clw1, clb1, clw2, clb2,
                                 rw1, rb1, rw2, rb2, out, nG);
}